// Round 1
// baseline (11907.579 us; speedup 1.0000x reference)
//
#include <hip/hip_runtime.h>

#define B_ 64
#define T_ 512
#define I_ 512
#define H_ 1024
#define PSH 65536     // shorts per plane (B_*H_); plane pair = hi+lo = 131072 shorts
#define G_ 64

typedef __attribute__((ext_vector_type(8))) short bf16x8;
typedef __attribute__((ext_vector_type(4))) float f32x4;

static __device__ __forceinline__ short f2bf(float f) {
  unsigned u = __float_as_uint(f);
  unsigned r = (u + 0x7fffu + ((u >> 16) & 1u)) >> 16;  // RNE
  return (short)(unsigned short)r;
}
static __device__ __forceinline__ float bf2f(short s) {
  return __uint_as_float(((unsigned)(unsigned short)s) << 16);
}
static __device__ __forceinline__ bf16x8 pack8(float4 u, float4 v) {
  bf16x8 r;
  r[0] = f2bf(u.x); r[1] = f2bf(u.y); r[2] = f2bf(u.z); r[3] = f2bf(u.w);
  r[4] = f2bf(v.x); r[5] = f2bf(v.y); r[6] = f2bf(v.z); r[7] = f2bf(v.w);
  return r;
}

// ---------------------------------------------------------------------------
// Kernel 1 (unchanged): pre = x @ Wi^T + bi + bh, in-place into d_out.
// ---------------------------------------------------------------------------
#define PBK 32
#define PLDA 40

__global__ __launch_bounds__(256) void proj_gemm(
    const float* __restrict__ x, const float* __restrict__ Wi,
    const float* __restrict__ bi, const float* __restrict__ bh,
    float* __restrict__ out) {
  __shared__ short As[128 * PLDA];
  __shared__ short Bs[128 * PLDA];
  const int tid = threadIdx.x;
  const int m0 = (blockIdx.x >> 3) * 128;
  const int n0 = (blockIdx.x & 7) * 128;
  const int wave = tid >> 6, lane = tid & 63;
  const int wm = (wave & 1) * 64, wn = (wave >> 1) * 64;
  const int lm = lane & 15, lq = lane >> 4;

  f32x4 acc[4][4];
#pragma unroll
  for (int i = 0; i < 4; ++i)
#pragma unroll
    for (int j = 0; j < 4; ++j) {
      f32x4 z = {0.f, 0.f, 0.f, 0.f};
      acc[i][j] = z;
    }

  const int lrow = tid >> 1;
  const int lcol = (tid & 1) * 16;
  const float* xp = x + (size_t)(m0 + lrow) * I_ + lcol;
  const float* wp = Wi + (size_t)(n0 + lrow) * I_ + lcol;

  for (int k0 = 0; k0 < I_; k0 += PBK) {
    float4 a0 = *(const float4*)(xp + k0);
    float4 a1 = *(const float4*)(xp + k0 + 4);
    float4 a2 = *(const float4*)(xp + k0 + 8);
    float4 a3 = *(const float4*)(xp + k0 + 12);
    float4 b0 = *(const float4*)(wp + k0);
    float4 b1 = *(const float4*)(wp + k0 + 4);
    float4 b2 = *(const float4*)(wp + k0 + 8);
    float4 b3 = *(const float4*)(wp + k0 + 12);
    __syncthreads();
    *(bf16x8*)&As[lrow * PLDA + lcol] = pack8(a0, a1);
    *(bf16x8*)&As[lrow * PLDA + lcol + 8] = pack8(a2, a3);
    *(bf16x8*)&Bs[lrow * PLDA + lcol] = pack8(b0, b1);
    *(bf16x8*)&Bs[lrow * PLDA + lcol + 8] = pack8(b2, b3);
    __syncthreads();

    bf16x8 af[4], bfr[4];
#pragma unroll
    for (int i = 0; i < 4; ++i)
      af[i] = *(const bf16x8*)&As[(wm + i * 16 + lm) * PLDA + lq * 8];
#pragma unroll
    for (int j = 0; j < 4; ++j)
      bfr[j] = *(const bf16x8*)&Bs[(wn + j * 16 + lm) * PLDA + lq * 8];
#pragma unroll
    for (int i = 0; i < 4; ++i)
#pragma unroll
      for (int j = 0; j < 4; ++j)
        acc[i][j] = __builtin_amdgcn_mfma_f32_16x16x32_bf16(af[i], bfr[j],
                                                            acc[i][j], 0, 0, 0);
  }

  const int rb = m0 + wm + lq * 4;
  const int cb = n0 + wn + lm;
#pragma unroll
  for (int j = 0; j < 4; ++j) {
    const int n = cb + j * 16;
    const float bias = bi[n] + bh[n];
#pragma unroll
    for (int i = 0; i < 4; ++i) {
      const int m = rb + i * 16;
#pragma unroll
      for (int r = 0; r < 4; ++r)
        out[(size_t)(m + r) * H_ + n] = acc[i][j][r] + bias;
    }
  }
}

// ---------------------------------------------------------------------------
// Agent-scope (L3-coherent, L2-bypassing) helpers.
// ---------------------------------------------------------------------------
static __device__ __forceinline__ unsigned long long ld_a8(const void* p) {
  return __hip_atomic_load((const unsigned long long*)p, __ATOMIC_RELAXED,
                           __HIP_MEMORY_SCOPE_AGENT);
}
static __device__ __forceinline__ void st_a2(unsigned short* p,
                                             unsigned short v) {
  __hip_atomic_store(p, v, __ATOMIC_RELAXED, __HIP_MEMORY_SCOPE_AGENT);
}

union frag_u {
  unsigned long long q[2];
  bf16x8 v;
};

#define TAGM 0x8000800080008000ULL

// ---------------------------------------------------------------------------
// Kernel 2: persistent recurrence, FLAGLESS self-tagged exchange.
//
// ReLU => h >= 0 => hi-plane sign bits free. hi = TRUNCATE(v) => lo = v-hi >= 0
// => lo-plane sign bits free too. Every stored short carries a 1-bit generation
// tag in its sign: tag(s) = ((s+1)>>1)&1 (per-plane alternating). Tag=1 steps
// store NEGATED values (xor 0x8000); the consumer runs MFMA on negated A-frags
// as-is and computes v = pre - rs instead of pre + rs -- tag strip is free.
//
// Consumer: per-block check+retry (AND/OR sign-fold of the 4 u64 loads). The
// poll load IS the data load: one L3 round trip on the critical path. No
// vmcnt(0) drain, no flags, no __syncthreads (waves are fully independent:
// wave wv exchanges only with same-wv waves via disjoint slots).
//
// Safety: per-2B self-tags detect any tearing; per-location coherence gives
// monotone slot history; skew between waves is < 2 steps (a writer cannot
// overwrite generation s-1 before reading everyone's step-s data), so the
// period-4 tag aliasing is unreachable. Startup: init plane-1 zeros (tag 0)
// -> vmcnt(0) -> plane-0 zeros (h_0, tag 0); consumers' plane-1 polls expect
// tag 1, so 0xAA poison (sign=1) can never false-positive: reaching step 2
// implies plane-0 init consumed which implies plane-1 init visible.
//
// Cross-step prefetch: the i>=24 tail of the block loop issues next-step
// blocks into the freed slots (stale reads are caught by the retry), so
// pipeline fill overlaps the epilogue and the producer's store latency.
// ---------------------------------------------------------------------------
template <int TR>
static __device__ __forceinline__ void rnn_step(
    const int s, const int wv, const int lq, const int kb0, const int np,
    const int Sbase, const int rdoff, const unsigned short flip,
    const bf16x8 (&Bh)[32], const bf16x8 (&Bl)[32],
    unsigned long long (&q)[8][4], unsigned short* __restrict__ planes,
    float* __restrict__ out, float* __restrict__ outH) {
  const int t = s - 1;
  size_t oidx[4];
  float pre[4];
#pragma unroll
  for (int r = 0; r < 4; ++r) {
    const int b = wv * 16 + lq * 4 + r;
    oidx[r] = (size_t)b * (T_ * H_) + (size_t)t * H_ + np;
    pre[r] = out[oidx[r]];  // overlaps the first-block spin
  }
  const char* src = (const char*)planes + (size_t)((s - 1) & 1) * 262144;
  const char* nxt = (const char*)planes + (size_t)(s & 1) * 262144;
  unsigned short* dst = planes + (size_t)(s & 1) * (2 * PSH);

  const f32x4 z = {0.f, 0.f, 0.f, 0.f};
  f32x4 c0 = z, c1 = z, c2 = z;
#pragma unroll
  for (int i = 0; i < 32; ++i) {
    const int sl = i & 7;
    const char* p = src + (((kb0 + i) & 31) * 4096) + rdoff;
    // self-tag check + retry: accept only when all 32 shorts carry tag TR
    for (;;) {
      const unsigned long long f =
          TR ? (q[sl][0] & q[sl][1] & q[sl][2] & q[sl][3])
             : (q[sl][0] | q[sl][1] | q[sl][2] | q[sl][3]);
      if (TR ? ((f & TAGM) == TAGM) : ((f & TAGM) == 0ULL)) break;
      q[sl][0] = ld_a8(p);
      q[sl][1] = ld_a8(p + 8);
      q[sl][2] = ld_a8(p + 131072);
      q[sl][3] = ld_a8(p + 131072 + 8);
    }
    frag_u ah, al;
    ah.q[0] = q[sl][0];
    ah.q[1] = q[sl][1];
    al.q[0] = q[sl][2];
    al.q[1] = q[sl][3];
    c0 = __builtin_amdgcn_mfma_f32_16x16x32_bf16(ah.v, Bh[i], c0, 0, 0, 0);
    c1 = __builtin_amdgcn_mfma_f32_16x16x32_bf16(ah.v, Bl[i], c1, 0, 0, 0);
    c2 = __builtin_amdgcn_mfma_f32_16x16x32_bf16(al.v, Bh[i], c2, 0, 0, 0);
    if (i < 24) {
      const char* p2 = src + (((kb0 + i + 8) & 31) * 4096) + rdoff;
      q[sl][0] = ld_a8(p2);
      q[sl][1] = ld_a8(p2 + 8);
      q[sl][2] = ld_a8(p2 + 131072);
      q[sl][3] = ld_a8(p2 + 131072 + 8);
    } else if (s < T_) {  // cross-step prefetch; retry next step handles stale
      const char* p2 = nxt + (((kb0 + (i - 24)) & 31) * 4096) + rdoff;
      q[sl][0] = ld_a8(p2);
      q[sl][1] = ld_a8(p2 + 8);
      q[sl][2] = ld_a8(p2 + 131072);
      q[sl][3] = ld_a8(p2 + 131072 + 8);
    }
  }
  const f32x4 rs = c0 + c1 + c2;

  // epilogue: tagged h stores FIRST (they are the signal), no drain needed
  float v[4];
#pragma unroll
  for (int r = 0; r < 4; ++r) {
    float a = TR ? (pre[r] - rs[r]) : (pre[r] + rs[r]);  // TR=1 data is negated
    a = a > 0.f ? a : 0.f;
    v[r] = a;
    const unsigned short hv = (unsigned short)(__float_as_uint(a) >> 16);  // trunc => lo>=0
    const float hf = __uint_as_float((unsigned)hv << 16);
    const unsigned short lv = (unsigned short)f2bf(a - hf);  // RNE, >= 0
    st_a2(&dst[Sbase + r * 8], (unsigned short)(hv ^ flip));
    st_a2(&dst[PSH + Sbase + r * 8], (unsigned short)(lv ^ flip));
  }
  // out writes off the critical chain
#pragma unroll
  for (int r = 0; r < 4; ++r) {
    out[oidx[r]] = v[r];
    if (s == T_) outH[(size_t)(wv * 16 + lq * 4 + r) * H_ + np] = v[r];
  }
}

__global__ __launch_bounds__(256, 1) void rnn_rec(
    const float* __restrict__ Wh, float* __restrict__ out,
    unsigned short* __restrict__ planes) {
  const int tid = threadIdx.x;
  const int g = blockIdx.x;
  const int n0 = g * 16;
  const int wv = tid >> 6;
  const int lane = tid & 63;
  const int lm = lane & 15, lq = lane >> 4;
  const int kb0 = g & 31;  // staggered K start

  // --- B-frags (hi+lo) into registers, rotated: Bh[i] holds km=(kb0+i)&31.
  bf16x8 Bh[32], Bl[32];
  {
    const float* wrow = Wh + (size_t)(n0 + lm) * H_ + lq * 8;
#pragma unroll
    for (int i = 0; i < 32; ++i) {
      const int km = (kb0 + i) & 31;
      float4 w0 = *(const float4*)(wrow + km * 32);
      float4 w1 = *(const float4*)(wrow + km * 32 + 4);
      float wf[8] = {w0.x, w0.y, w0.z, w0.w, w1.x, w1.y, w1.z, w1.w};
      bf16x8 hi, lo;
#pragma unroll
      for (int j = 0; j < 8; ++j) {
        hi[j] = f2bf(wf[j]);
        lo[j] = f2bf(wf[j] - bf2f(hi[j]));
      }
      Bh[i] = hi;
      Bl[i] = lo;
    }
  }

  // --- producer constants: thread owns (b = wv*16 + lq*4 + r, np) ---
  const int np = n0 + lm;
  const int kbp = np >> 5, qp = (np >> 3) & 3, jp = np & 7;
  const int Sbase = (kbp * 4 + wv) * 512 + qp * 128 + lq * 32 + jp;
  const int rdoff = wv * 1024 + lane * 16;  // byte offset within a km sub-block row

  // --- startup: plane-1 zeros (tag 0) -> drain -> plane-0 zeros (h_0, tag 0).
  // Order matters: consumers at s=2 poll plane 1 for tag 1; having consumed
  // plane-0 init implies plane-1 init visible, so 0xAA poison is unreachable.
  unsigned short* pl1 = planes + 2 * PSH;
#pragma unroll
  for (int r = 0; r < 4; ++r) {
    st_a2(&pl1[Sbase + r * 8], 0);
    st_a2(&pl1[PSH + Sbase + r * 8], 0);
  }
  asm volatile("s_waitcnt vmcnt(0)" ::: "memory");
#pragma unroll
  for (int r = 0; r < 4; ++r) {
    st_a2(&planes[Sbase + r * 8], 0);
    st_a2(&planes[PSH + Sbase + r * 8], 0);
  }

  // --- prime the depth-8 pipeline for step 1 (plane pair 0; retry absorbs
  // not-yet-initialized slots) ---
  unsigned long long q[8][4];
#pragma unroll
  for (int i = 0; i < 8; ++i) {
    const char* p = (const char*)planes + (((kb0 + i) & 31) * 4096) + rdoff;
    q[i][0] = ld_a8(p);
    q[i][1] = ld_a8(p + 8);
    q[i][2] = ld_a8(p + 131072);
    q[i][3] = ld_a8(p + 131072 + 8);
  }

  float* outH = out + (size_t)B_ * T_ * H_;
  // tag schedule period 4: TR(s) = (s>>1)&1 -> {0,1,1,0}; flip(s) =
  // (((s+1)>>1)&1)<<15 -> {0x8000,0x8000,0,0} for s = 1,2,3,4 (mod 4).
  for (int sb = 1; sb <= T_; sb += 4) {
    rnn_step<0>(sb + 0, wv, lq, kb0, np, Sbase, rdoff, 0x8000, Bh, Bl, q,
                planes, out, outH);
    rnn_step<1>(sb + 1, wv, lq, kb0, np, Sbase, rdoff, 0x8000, Bh, Bl, q,
                planes, out, outH);
    rnn_step<1>(sb + 2, wv, lq, kb0, np, Sbase, rdoff, 0x0000, Bh, Bl, q,
                planes, out, outH);
    rnn_step<0>(sb + 3, wv, lq, kb0, np, Sbase, rdoff, 0x0000, Bh, Bl, q,
                planes, out, outH);
  }
}

// ---------------------------------------------------------------------------
extern "C" void kernel_launch(void* const* d_in, const int* in_sizes, int n_in,
                              void* d_out, int out_size, void* d_ws,
                              size_t ws_size, hipStream_t stream) {
  const float* x = (const float*)d_in[0];   // [B,T,I]
  const float* Wi = (const float*)d_in[1];  // [H,I]
  const float* bi = (const float*)d_in[2];  // [H]
  const float* Wh = (const float*)d_in[3];  // [H,H]
  const float* bh = (const float*)d_in[4];  // [H]
  float* out = (float*)d_out;

  unsigned short* planes = (unsigned short*)d_ws;  // 2 pairs x 256 KB = 512 KB

  proj_gemm<<<2048, 256, 0, stream>>>(x, Wi, bi, bh, out);
  rnn_rec<<<G_, 256, 0, stream>>>(Wh, out, planes);
}

// Round 3
// 7655.116 us; speedup vs baseline: 1.5555x; 1.5555x over previous
//
#include <hip/hip_runtime.h>

#define B_ 64
#define T_ 512
#define I_ 512
#define H_ 1024
#define PSH 65536     // shorts per plane (B_*H_); plane pair = hi+lo = 131072 shorts
#define FPAD 16       // pad flags to 64 B lines
#define G_ 64

typedef __attribute__((ext_vector_type(8))) short bf16x8;
typedef __attribute__((ext_vector_type(4))) float f32x4;

static __device__ __forceinline__ short f2bf(float f) {
  unsigned u = __float_as_uint(f);
  unsigned r = (u + 0x7fffu + ((u >> 16) & 1u)) >> 16;  // RNE
  return (short)(unsigned short)r;
}
static __device__ __forceinline__ float bf2f(short s) {
  return __uint_as_float(((unsigned)(unsigned short)s) << 16);
}
static __device__ __forceinline__ bf16x8 pack8(float4 u, float4 v) {
  bf16x8 r;
  r[0] = f2bf(u.x); r[1] = f2bf(u.y); r[2] = f2bf(u.z); r[3] = f2bf(u.w);
  r[4] = f2bf(v.x); r[5] = f2bf(v.y); r[6] = f2bf(v.z); r[7] = f2bf(v.w);
  return r;
}

// ---------------------------------------------------------------------------
// Kernel 1 (unchanged): pre = x @ Wi^T + bi + bh, in-place into d_out.
// ---------------------------------------------------------------------------
#define PBK 32
#define PLDA 40

__global__ __launch_bounds__(256) void proj_gemm(
    const float* __restrict__ x, const float* __restrict__ Wi,
    const float* __restrict__ bi, const float* __restrict__ bh,
    float* __restrict__ out) {
  __shared__ short As[128 * PLDA];
  __shared__ short Bs[128 * PLDA];
  const int tid = threadIdx.x;
  const int m0 = (blockIdx.x >> 3) * 128;
  const int n0 = (blockIdx.x & 7) * 128;
  const int wave = tid >> 6, lane = tid & 63;
  const int wm = (wave & 1) * 64, wn = (wave >> 1) * 64;
  const int lm = lane & 15, lq = lane >> 4;

  f32x4 acc[4][4];
#pragma unroll
  for (int i = 0; i < 4; ++i)
#pragma unroll
    for (int j = 0; j < 4; ++j) {
      f32x4 z = {0.f, 0.f, 0.f, 0.f};
      acc[i][j] = z;
    }

  const int lrow = tid >> 1;
  const int lcol = (tid & 1) * 16;
  const float* xp = x + (size_t)(m0 + lrow) * I_ + lcol;
  const float* wp = Wi + (size_t)(n0 + lrow) * I_ + lcol;

  for (int k0 = 0; k0 < I_; k0 += PBK) {
    float4 a0 = *(const float4*)(xp + k0);
    float4 a1 = *(const float4*)(xp + k0 + 4);
    float4 a2 = *(const float4*)(xp + k0 + 8);
    float4 a3 = *(const float4*)(xp + k0 + 12);
    float4 b0 = *(const float4*)(wp + k0);
    float4 b1 = *(const float4*)(wp + k0 + 4);
    float4 b2 = *(const float4*)(wp + k0 + 8);
    float4 b3 = *(const float4*)(wp + k0 + 12);
    __syncthreads();
    *(bf16x8*)&As[lrow * PLDA + lcol] = pack8(a0, a1);
    *(bf16x8*)&As[lrow * PLDA + lcol + 8] = pack8(a2, a3);
    *(bf16x8*)&Bs[lrow * PLDA + lcol] = pack8(b0, b1);
    *(bf16x8*)&Bs[lrow * PLDA + lcol + 8] = pack8(b2, b3);
    __syncthreads();

    bf16x8 af[4], bfr[4];
#pragma unroll
    for (int i = 0; i < 4; ++i)
      af[i] = *(const bf16x8*)&As[(wm + i * 16 + lm) * PLDA + lq * 8];
#pragma unroll
    for (int j = 0; j < 4; ++j)
      bfr[j] = *(const bf16x8*)&Bs[(wn + j * 16 + lm) * PLDA + lq * 8];
#pragma unroll
    for (int i = 0; i < 4; ++i)
#pragma unroll
      for (int j = 0; j < 4; ++j)
        acc[i][j] = __builtin_amdgcn_mfma_f32_16x16x32_bf16(af[i], bfr[j],
                                                            acc[i][j], 0, 0, 0);
  }

  const int rb = m0 + wm + lq * 4;
  const int cb = n0 + wn + lm;
#pragma unroll
  for (int j = 0; j < 4; ++j) {
    const int n = cb + j * 16;
    const float bias = bi[n] + bh[n];
#pragma unroll
    for (int i = 0; i < 4; ++i) {
      const int m = rb + i * 16;
#pragma unroll
      for (int r = 0; r < 4; ++r)
        out[(size_t)(m + r) * H_ + n] = acc[i][j][r] + bias;
    }
  }
}

// ---------------------------------------------------------------------------
// Agent-scope (L3-coherent, L2-bypassing) helpers.
// ---------------------------------------------------------------------------
static __device__ __forceinline__ unsigned long long ld_a8(const void* p) {
  return __hip_atomic_load((const unsigned long long*)p, __ATOMIC_RELAXED,
                           __HIP_MEMORY_SCOPE_AGENT);
}
static __device__ __forceinline__ void st_a2(unsigned short* p,
                                             unsigned short v) {
  __hip_atomic_store(p, v, __ATOMIC_RELAXED, __HIP_MEMORY_SCOPE_AGENT);
}
static __device__ __forceinline__ int ld_flag(const int* p) {
  return __hip_atomic_load(p, __ATOMIC_RELAXED, __HIP_MEMORY_SCOPE_AGENT);
}

union frag_u {
  unsigned long long q[2];
  bf16x8 v;
};

#define TAGM 0x8000800080008000ULL

// ---------------------------------------------------------------------------
// Kernel 2: persistent recurrence. HYBRID sync (R2 design, R0 register budget):
//   - self-tagged planes: ReLU => h>=0; hi=TRUNC(v) => lo=v-hi>=0 => every
//     stored short's sign bit is a free 1-bit generation tag. Tag=1 steps
//     store negated values (xor 0x8000); consumer MFMAs them as-is and
//     computes v = pre - rs. Tags are the CORRECTNESS gate: stale/torn reads
//     are detected per-16B fragment and retried (backed off, cold path).
//   - per-wave ADVISORY flags (pacing only): producer wave issues its 8 data
//     stores then immediately stores its flag (NO vmcnt drain, NO
//     __syncthreads -- exchange is wave-to-wave: consumer wave wv reads only
//     slot rows (kb*4+wv) written by producer wave wv of each WG). Consumer
//     waits flag>=s-1 before issuing data loads, so post-gate loads are
//     ~always fresh.
// vs R0 this removes from the serial chain: store-drain RT, __syncthreads
// convergence, and flag-behind-drain visibility. vs R1: no stale prefetch
// (loads only post-gate), sleep backoff in retries (no congestion collapse).
// Depth-8 slot pipeline = R0's proven 256-VGPR budget (R2's depth-16 likely
// spilled -> container timeout).
// Ping-pong reuse safe w/o drains: producer overwrites plane s&1 only after
// tag-validating all of h_{s-1} (wave-wv rows), whose stores each wave issues
// only after its plane-(s&1) reads of h_{s-2} returned (data dep thru MFMA).
// Tag aliasing needs skew>=2 steps; the validation chain bounds skew<2.
// ---------------------------------------------------------------------------
template <int TR>
static __device__ __forceinline__ void rnn_step(
    const int s, const int wv, const int lane, const int lq, const int kb0,
    const int np, const int Sbase, const int rdoff, const int fpoll,
    const int fstore, const unsigned short flip, const bf16x8 (&Bh)[32],
    const bf16x8 (&Bl)[32], unsigned short* __restrict__ planes,
    int* __restrict__ flags, float* __restrict__ out,
    float* __restrict__ outH) {
  const int t = s - 1;
  size_t oidx[4];
  float pre[4];
#pragma unroll
  for (int r = 0; r < 4; ++r) {
    const int b = wv * 16 + lq * 4 + r;
    oidx[r] = (size_t)b * (T_ * H_) + (size_t)t * H_ + np;
    pre[r] = out[oidx[r]];  // overlaps the gate poll
  }

  // advisory pacing gate: lane l polls WG l's wave-wv flag
  const int need = s - 1;
  for (;;) {
    const int f = ld_flag(&flags[fpoll]);
    if (__all(f >= need)) break;
    __builtin_amdgcn_s_sleep(1);
  }

  const char* src = (const char*)planes + (size_t)((s - 1) & 1) * 262144;
  unsigned short* dst = planes + (size_t)(s & 1) * (2 * PSH);

  // issue 8 blocks (32 loads) post-gate; ~always valid on first check
  unsigned long long q[8][4];
#pragma unroll
  for (int i = 0; i < 8; ++i) {
    const char* p = src + (((kb0 + i) & 31) * 4096) + rdoff;
    q[i][0] = ld_a8(p);
    q[i][1] = ld_a8(p + 8);
    q[i][2] = ld_a8(p + 131072);
    q[i][3] = ld_a8(p + 131072 + 8);
  }

  const f32x4 z = {0.f, 0.f, 0.f, 0.f};
  f32x4 c0 = z, c1 = z, c2 = z;
#pragma unroll
  for (int i = 0; i < 32; ++i) {
    const int sl = i & 7;
    const char* p = src + (((kb0 + i) & 31) * 4096) + rdoff;
    // self-tag check + backed-off retry (cold path)
    for (;;) {
      const unsigned long long f =
          TR ? (q[sl][0] & q[sl][1] & q[sl][2] & q[sl][3])
             : (q[sl][0] | q[sl][1] | q[sl][2] | q[sl][3]);
      if (TR ? ((f & TAGM) == TAGM) : ((f & TAGM) == 0ULL)) break;
      __builtin_amdgcn_s_sleep(1);
      q[sl][0] = ld_a8(p);
      q[sl][1] = ld_a8(p + 8);
      q[sl][2] = ld_a8(p + 131072);
      q[sl][3] = ld_a8(p + 131072 + 8);
    }
    frag_u ah, al;
    ah.q[0] = q[sl][0];
    ah.q[1] = q[sl][1];
    al.q[0] = q[sl][2];
    al.q[1] = q[sl][3];
    c0 = __builtin_amdgcn_mfma_f32_16x16x32_bf16(ah.v, Bh[i], c0, 0, 0, 0);
    c1 = __builtin_amdgcn_mfma_f32_16x16x32_bf16(ah.v, Bl[i], c1, 0, 0, 0);
    c2 = __builtin_amdgcn_mfma_f32_16x16x32_bf16(al.v, Bh[i], c2, 0, 0, 0);
    if (i < 24) {  // refill freed slot with block i+8 (same step, same plane)
      const char* p2 = src + (((kb0 + i + 8) & 31) * 4096) + rdoff;
      q[sl][0] = ld_a8(p2);
      q[sl][1] = ld_a8(p2 + 8);
      q[sl][2] = ld_a8(p2 + 131072);
      q[sl][3] = ld_a8(p2 + 131072 + 8);
    }
  }
  const f32x4 rs = c0 + c1 + c2;

  // epilogue: tagged h stores first, flag immediately after (no drain)
  float v[4];
#pragma unroll
  for (int r = 0; r < 4; ++r) {
    float a = TR ? (pre[r] - rs[r]) : (pre[r] + rs[r]);  // TR=1 data negated
    a = a > 0.f ? a : 0.f;
    v[r] = a;
    const unsigned short hv =
        (unsigned short)(__float_as_uint(a) >> 16);  // trunc => lo >= 0
    const float hf = __uint_as_float((unsigned)hv << 16);
    const unsigned short lv = (unsigned short)f2bf(a - hf);  // RNE, >= 0
    st_a2(&dst[Sbase + r * 8], (unsigned short)(hv ^ flip));
    st_a2(&dst[PSH + Sbase + r * 8], (unsigned short)(lv ^ flip));
  }
  if (lane == 0)
    __hip_atomic_store(&flags[fstore], s, __ATOMIC_RELAXED,
                       __HIP_MEMORY_SCOPE_AGENT);
  // out writes off the critical chain
#pragma unroll
  for (int r = 0; r < 4; ++r) {
    out[oidx[r]] = v[r];
    if (s == T_) outH[(size_t)(wv * 16 + lq * 4 + r) * H_ + np] = v[r];
  }
}

__global__ __launch_bounds__(256, 1) void rnn_rec(
    const float* __restrict__ Wh, float* __restrict__ out,
    unsigned short* __restrict__ planes, int* __restrict__ flags) {
  const int tid = threadIdx.x;
  const int g = blockIdx.x;
  const int n0 = g * 16;
  const int wv = tid >> 6;
  const int lane = tid & 63;
  const int lm = lane & 15, lq = lane >> 4;
  const int kb0 = g & 31;  // staggered K start

  // --- B-frags (hi+lo) into registers, rotated: Bh[i] holds km=(kb0+i)&31.
  bf16x8 Bh[32], Bl[32];
  {
    const float* wrow = Wh + (size_t)(n0 + lm) * H_ + lq * 8;
#pragma unroll
    for (int i = 0; i < 32; ++i) {
      const int km = (kb0 + i) & 31;
      float4 w0 = *(const float4*)(wrow + km * 32);
      float4 w1 = *(const float4*)(wrow + km * 32 + 4);
      float wf[8] = {w0.x, w0.y, w0.z, w0.w, w1.x, w1.y, w1.z, w1.w};
      bf16x8 hi, lo;
#pragma unroll
      for (int j = 0; j < 8; ++j) {
        hi[j] = f2bf(wf[j]);
        lo[j] = f2bf(wf[j] - bf2f(hi[j]));
      }
      Bh[i] = hi;
      Bl[i] = lo;
    }
  }

  // --- producer constants: thread owns (b = wv*16 + lq*4 + r, np) ---
  const int np = n0 + lm;
  const int kbp = np >> 5, qp = (np >> 3) & 3, jp = np & 7;
  const int Sbase = (kbp * 4 + wv) * 512 + qp * 128 + lq * 32 + jp;
  const int rdoff = wv * 1024 + lane * 16;   // byte offset within a km block
  const int fpoll = (lane * 4 + wv) * FPAD;  // poll WG 'lane', wave wv
  const int fstore = (g * 4 + wv) * FPAD;    // own flag

  // --- startup: plane-1 zeros (tag 0) -> drain -> plane-0 zeros (h_0, tag 0)
  // -> drain -> flag=0. Gate@s=1 then implies both inits visible; tags
  // backstop. 0xAA poison (sign=1) never accepted by a TR=0 check.
  unsigned short* pl1 = planes + 2 * PSH;
#pragma unroll
  for (int r = 0; r < 4; ++r) {
    st_a2(&pl1[Sbase + r * 8], 0);
    st_a2(&pl1[PSH + Sbase + r * 8], 0);
  }
  asm volatile("s_waitcnt vmcnt(0)" ::: "memory");
#pragma unroll
  for (int r = 0; r < 4; ++r) {
    st_a2(&planes[Sbase + r * 8], 0);
    st_a2(&planes[PSH + Sbase + r * 8], 0);
  }
  asm volatile("s_waitcnt vmcnt(0)" ::: "memory");
  if (lane == 0)
    __hip_atomic_store(&flags[fstore], 0, __ATOMIC_RELAXED,
                       __HIP_MEMORY_SCOPE_AGENT);

  float* outH = out + (size_t)B_ * T_ * H_;
  // tag schedule period 4: gen s stored with tag {1,1,0,0} for s mod 4 =
  // {1,2,3,0}; consumer of gen s-1 at step s uses TR = {0,1,1,0}.
  for (int sb = 1; sb <= T_; sb += 4) {
    rnn_step<0>(sb + 0, wv, lane, lq, kb0, np, Sbase, rdoff, fpoll, fstore,
                0x8000, Bh, Bl, planes, flags, out, outH);
    rnn_step<1>(sb + 1, wv, lane, lq, kb0, np, Sbase, rdoff, fpoll, fstore,
                0x8000, Bh, Bl, planes, flags, out, outH);
    rnn_step<1>(sb + 2, wv, lane, lq, kb0, np, Sbase, rdoff, fpoll, fstore,
                0x0000, Bh, Bl, planes, flags, out, outH);
    rnn_step<0>(sb + 3, wv, lane, lq, kb0, np, Sbase, rdoff, fpoll, fstore,
                0x0000, Bh, Bl, planes, flags, out, outH);
  }
}

// ---------------------------------------------------------------------------
extern "C" void kernel_launch(void* const* d_in, const int* in_sizes, int n_in,
                              void* d_out, int out_size, void* d_ws,
                              size_t ws_size, hipStream_t stream) {
  const float* x = (const float*)d_in[0];   // [B,T,I]
  const float* Wi = (const float*)d_in[1];  // [H,I]
  const float* bi = (const float*)d_in[2];  // [H]
  const float* Wh = (const float*)d_in[3];  // [H,H]
  const float* bh = (const float*)d_in[4];  // [H]
  float* out = (float*)d_out;

  int* flags = (int*)d_ws;  // 64 WGs x 4 waves x 64 B = 16 KB
  unsigned short* planes =
      (unsigned short*)((char*)d_ws + G_ * 4 * FPAD * 4);  // 2 pairs x 256 KB

  proj_gemm<<<2048, 256, 0, stream>>>(x, Wi, bi, bh, out);
  rnn_rec<<<G_, 256, 0, stream>>>(Wh, out, planes, flags);
}

// Round 5
// 2772.520 us; speedup vs baseline: 4.2949x; 2.7611x over previous
//
#include <hip/hip_runtime.h>

#define B_ 64
#define T_ 512
#define I_ 512
#define H_ 1024
#define FPAD 16       // pad flags to 64 B lines
#define TPS 16384     // shorts per team plane (16 rows x 1024 cols)
#define NWG 256       // 4 teams x 64 WGs

typedef __attribute__((ext_vector_type(8))) short bf16x8;
typedef __attribute__((ext_vector_type(4))) float f32x4;

static __device__ __forceinline__ short f2bf(float f) {
  unsigned u = __float_as_uint(f);
  unsigned r = (u + 0x7fffu + ((u >> 16) & 1u)) >> 16;  // RNE
  return (short)(unsigned short)r;
}
static __device__ __forceinline__ float bf2f(short s) {
  return __uint_as_float(((unsigned)(unsigned short)s) << 16);
}
static __device__ __forceinline__ bf16x8 pack8(float4 u, float4 v) {
  bf16x8 r;
  r[0] = f2bf(u.x); r[1] = f2bf(u.y); r[2] = f2bf(u.z); r[3] = f2bf(u.w);
  r[4] = f2bf(v.x); r[5] = f2bf(v.y); r[6] = f2bf(v.z); r[7] = f2bf(v.w);
  return r;
}

// ---------------------------------------------------------------------------
// Kernel 1 (unchanged): pre = x @ Wi^T + bi + bh, in-place into d_out.
// ---------------------------------------------------------------------------
#define PBK 32
#define PLDA 40

__global__ __launch_bounds__(256) void proj_gemm(
    const float* __restrict__ x, const float* __restrict__ Wi,
    const float* __restrict__ bi, const float* __restrict__ bh,
    float* __restrict__ out) {
  __shared__ short As[128 * PLDA];
  __shared__ short Bs[128 * PLDA];
  const int tid = threadIdx.x;
  const int m0 = (blockIdx.x >> 3) * 128;
  const int n0 = (blockIdx.x & 7) * 128;
  const int wave = tid >> 6, lane = tid & 63;
  const int wm = (wave & 1) * 64, wn = (wave >> 1) * 64;
  const int lm = lane & 15, lq = lane >> 4;

  f32x4 acc[4][4];
#pragma unroll
  for (int i = 0; i < 4; ++i)
#pragma unroll
    for (int j = 0; j < 4; ++j) {
      f32x4 z = {0.f, 0.f, 0.f, 0.f};
      acc[i][j] = z;
    }

  const int lrow = tid >> 1;
  const int lcol = (tid & 1) * 16;
  const float* xp = x + (size_t)(m0 + lrow) * I_ + lcol;
  const float* wp = Wi + (size_t)(n0 + lrow) * I_ + lcol;

  for (int k0 = 0; k0 < I_; k0 += PBK) {
    float4 a0 = *(const float4*)(xp + k0);
    float4 a1 = *(const float4*)(xp + k0 + 4);
    float4 a2 = *(const float4*)(xp + k0 + 8);
    float4 a3 = *(const float4*)(xp + k0 + 12);
    float4 b0 = *(const float4*)(wp + k0);
    float4 b1 = *(const float4*)(wp + k0 + 4);
    float4 b2 = *(const float4*)(wp + k0 + 8);
    float4 b3 = *(const float4*)(wp + k0 + 12);
    __syncthreads();
    *(bf16x8*)&As[lrow * PLDA + lcol] = pack8(a0, a1);
    *(bf16x8*)&As[lrow * PLDA + lcol + 8] = pack8(a2, a3);
    *(bf16x8*)&Bs[lrow * PLDA + lcol] = pack8(b0, b1);
    *(bf16x8*)&Bs[lrow * PLDA + lcol + 8] = pack8(b2, b3);
    __syncthreads();

    bf16x8 af[4], bfr[4];
#pragma unroll
    for (int i = 0; i < 4; ++i)
      af[i] = *(const bf16x8*)&As[(wm + i * 16 + lm) * PLDA + lq * 8];
#pragma unroll
    for (int j = 0; j < 4; ++j)
      bfr[j] = *(const bf16x8*)&Bs[(wn + j * 16 + lm) * PLDA + lq * 8];
#pragma unroll
    for (int i = 0; i < 4; ++i)
#pragma unroll
      for (int j = 0; j < 4; ++j)
        acc[i][j] = __builtin_amdgcn_mfma_f32_16x16x32_bf16(af[i], bfr[j],
                                                            acc[i][j], 0, 0, 0);
  }

  const int rb = m0 + wm + lq * 4;
  const int cb = n0 + wn + lm;
#pragma unroll
  for (int j = 0; j < 4; ++j) {
    const int n = cb + j * 16;
    const float bias = bi[n] + bh[n];
#pragma unroll
    for (int i = 0; i < 4; ++i) {
      const int m = rb + i * 16;
#pragma unroll
      for (int r = 0; r < 4; ++r)
        out[(size_t)(m + r) * H_ + n] = acc[i][j][r] + bias;
    }
  }
}

// ---------------------------------------------------------------------------
// Agent-scope (L3-coherent) helpers.
// ---------------------------------------------------------------------------
static __device__ __forceinline__ unsigned long long ld_a8(const void* p) {
  return __hip_atomic_load((const unsigned long long*)p, __ATOMIC_RELAXED,
                           __HIP_MEMORY_SCOPE_AGENT);
}
static __device__ __forceinline__ void st_a2(unsigned short* p,
                                             unsigned short v) {
  __hip_atomic_store(p, v, __ATOMIC_RELAXED, __HIP_MEMORY_SCOPE_AGENT);
}
static __device__ __forceinline__ int ld_flag(const int* p) {
  return __hip_atomic_load(p, __ATOMIC_RELAXED, __HIP_MEMORY_SCOPE_AGENT);
}

union frag_u {
  unsigned long long q[2];
  bf16x8 v;
};

// ---------------------------------------------------------------------------
// Kernel 2 (R5 = R4 design, resubmitted after infra failure; write-gate spin
// moved before the reduction barrier so it overlaps barrier convergence).
//
// Batch-team decomposition: h_s[b][:] depends only on row b of h_{s-1}, so
// batch splits into 4 INDEPENDENT teams of 16 rows. 256 WGs total:
// team = wg>>6 (rows 16t..16t+15), w = wg&63 (output cols 16w..16w+15). The 4
// waves k-split (wave wv: k in [256wv, 256wv+256)) and reduce via LDS.
//
// Per team, plane pair (ping-pong by s&1) holds h in MFMA A-frag order:
// short idx of h[r][c] = (c>>5)*512 + ((c>>3)&3)*128 + r*8 + (c&7); consumer
// lane l of k-block kb reads 16 B at byte kb*1024 + l*16 (R0's proven layout).
// hi plane at +0, lo at +TPS shorts (split hi=RNE bf16, lo=residual).
//
// Sync = R0's PROVEN semantics (R1/R3 showed removing the drain converts
// producer-side store-landing wait into consumer-side serialized stale-read
// discovery -- strictly worse): stores -> vmcnt(0) -> __syncthreads -> flag.
//   read gate  (step start): the wave's 16 producers (cols of its k-range)
//                            have flag >= s-1  => their h_{s-1} is at L3.
//   write gate (pre-barrier): all 64 team flags >= s-1 => everyone's reads of
//                            h_{s-2} (plane s&1) retired => overwrite safe.
//                            Polled between LDS partial-write and the
//                            reduction barrier; completes before any h-store.
// Deadlock-free by induction: the WG at the global-min flag value has both
// gates satisfied, so it always advances.
// Per wave per step: 8 A-blocks (256 B/lane, all issued post-gate, NO
// refills), 24 MFMAs, LDS reduce, 2 shorts stored. Stagger: block order
// rotated by w so WGs hit different L3 lines.
// ---------------------------------------------------------------------------
__global__ __launch_bounds__(256, 1) void rnn_rec(
    const float* __restrict__ Wh, float* __restrict__ out,
    unsigned short* __restrict__ planes, int* __restrict__ flags) {
  const int tid = threadIdx.x;
  const int wg = blockIdx.x;
  const int team = wg >> 6;
  const int w = wg & 63;
  const int wv = tid >> 6;
  const int lane = tid & 63;
  const int lm = lane & 15, lq = lane >> 4;

  // --- B-frags: Wh[16w+lm][256wv + kbl*32 + lq*8 + j], rotated kbl=(w+i)&7
  bf16x8 Bh[8], Bl[8];
  {
    const float* wrow = Wh + (size_t)(16 * w + lm) * H_ + wv * 256 + lq * 8;
#pragma unroll
    for (int i = 0; i < 8; ++i) {
      const int kbl = (w + i) & 7;
      float4 w0 = *(const float4*)(wrow + kbl * 32);
      float4 w1 = *(const float4*)(wrow + kbl * 32 + 4);
      float wf[8] = {w0.x, w0.y, w0.z, w0.w, w1.x, w1.y, w1.z, w1.w};
      bf16x8 hi, lo;
#pragma unroll
      for (int j = 0; j < 8; ++j) {
        hi[j] = f2bf(wf[j]);
        lo[j] = f2bf(wf[j] - bf2f(hi[j]));
      }
      Bh[i] = hi;
      Bl[i] = lo;
    }
  }

  // --- producer constants: thread owns (r = tid>>4, c = 16w + (tid&15)) ---
  const int r = tid >> 4;
  const int cl = tid & 15;
  const int c = 16 * w + cl;
  const int b = team * 16 + r;  // global batch row
  const int Sidx = (c >> 5) * 512 + ((c >> 3) & 3) * 128 + r * 8 + (c & 7);

  unsigned short* tbase = planes + (size_t)team * 4 * TPS;  // team plane base
  const int* frd = flags + (team * 64 + 16 * wv + lm) * FPAD;  // read gate
  const int* fwr = flags + (team * 64 + lane) * FPAD;          // write gate
  const int fown = wg * FPAD;

  // --- startup: zero own h_0 slots (pair 0, hi+lo) -> drain -> sync -> flag=0
  st_a2(tbase + Sidx, 0);
  st_a2(tbase + TPS + Sidx, 0);
  asm volatile("s_waitcnt vmcnt(0)" ::: "memory");
  __syncthreads();
  if (tid == 0)
    __hip_atomic_store(&flags[fown], 0, __ATOMIC_RELAXED,
                       __HIP_MEMORY_SCOPE_AGENT);

  float* outH = out + (size_t)B_ * T_ * H_;
  __shared__ float red[4][64][4];  // 4 KB k-partial reduction buffer
  const int lp = (r >> 2) * 16 + cl;  // reduction source lane
  const int ri = r & 3;               // reduction source reg

  for (int s = 1; s <= T_; ++s) {
    const int t = s - 1;
    const size_t oidx = (size_t)b * (T_ * H_) + (size_t)t * H_ + c;
    const float pre = out[oidx];  // L2-private; overlaps the read gate

    // read gate: my 16 producers have h_{s-1} at L3 (flag posts AFTER drain)
    const int need = s - 1;
    for (;;) {
      const int f = ld_flag(frd);
      if (__all(f >= need)) break;
      __builtin_amdgcn_s_sleep(1);
    }

    // all 8 A-blocks (hi+lo), issued back-to-back post-gate; no refills
    const char* src = (const char*)(tbase + (size_t)((s - 1) & 1) * 2 * TPS);
    unsigned long long q[8][4];
#pragma unroll
    for (int i = 0; i < 8; ++i) {
      const int kb = 8 * wv + ((w + i) & 7);
      const char* p = src + kb * 1024 + lane * 16;
      q[i][0] = ld_a8(p);
      q[i][1] = ld_a8(p + 8);
      q[i][2] = ld_a8(p + 32768);      // lo plane (+TPS shorts)
      q[i][3] = ld_a8(p + 32768 + 8);
    }

    const f32x4 z = {0.f, 0.f, 0.f, 0.f};
    f32x4 c0 = z, c1 = z, c2 = z;
#pragma unroll
    for (int i = 0; i < 8; ++i) {
      frag_u ah, al;
      ah.q[0] = q[i][0];
      ah.q[1] = q[i][1];
      al.q[0] = q[i][2];
      al.q[1] = q[i][3];
      c0 = __builtin_amdgcn_mfma_f32_16x16x32_bf16(ah.v, Bh[i], c0, 0, 0, 0);
      c1 = __builtin_amdgcn_mfma_f32_16x16x32_bf16(ah.v, Bl[i], c1, 0, 0, 0);
      c2 = __builtin_amdgcn_mfma_f32_16x16x32_bf16(al.v, Bh[i], c2, 0, 0, 0);
    }
    const f32x4 rs = c0 + c1 + c2;

    // LDS partial write, then write gate (overlaps barrier convergence):
    // all team flags >= s-1 => plane (s&1) reads of h_{s-2} retired.
    *(f32x4*)&red[wv][lane][0] = rs;
    for (;;) {
      const int f = ld_flag(fwr);
      if (__all(f >= need)) break;
      __builtin_amdgcn_s_sleep(1);
    }
    __syncthreads();
    const float sum = red[0][lp][ri] + red[1][lp][ri] + red[2][lp][ri] +
                      red[3][lp][ri];
    float v = pre + sum;
    v = v > 0.f ? v : 0.f;

    // h stores -> drain -> WG convergence -> flag (R0-proven ordering)
    unsigned short* dst = tbase + (size_t)(s & 1) * 2 * TPS;
    const short hv = f2bf(v);
    const short lv = f2bf(v - bf2f(hv));
    st_a2(dst + Sidx, (unsigned short)hv);
    st_a2(dst + TPS + Sidx, (unsigned short)lv);
    asm volatile("s_waitcnt vmcnt(0)" ::: "memory");
    __syncthreads();
    if (tid == 0)
      __hip_atomic_store(&flags[fown], s, __ATOMIC_RELAXED,
                         __HIP_MEMORY_SCOPE_AGENT);

    // out writes off the critical chain (thread-private locations, L2-cached)
    out[oidx] = v;
    if (s == T_) outH[(size_t)b * H_ + c] = v;
  }
}

// ---------------------------------------------------------------------------
extern "C" void kernel_launch(void* const* d_in, const int* in_sizes, int n_in,
                              void* d_out, int out_size, void* d_ws,
                              size_t ws_size, hipStream_t stream) {
  const float* x = (const float*)d_in[0];   // [B,T,I]
  const float* Wi = (const float*)d_in[1];  // [H,I]
  const float* bi = (const float*)d_in[2];  // [H]
  const float* Wh = (const float*)d_in[3];  // [H,H]
  const float* bh = (const float*)d_in[4];  // [H]
  float* out = (float*)d_out;

  int* flags = (int*)d_ws;  // 256 WGs x 64 B = 16 KB
  unsigned short* planes =
      (unsigned short*)((char*)d_ws + NWG * FPAD * 4);  // 4 teams x 128 KB

  proj_gemm<<<2048, 256, 0, stream>>>(x, Wi, bi, bh, out);
  rnn_rec<<<NWG, 256, 0, stream>>>(Wh, out, planes, flags);
}

// Round 6
// 2723.779 us; speedup vs baseline: 4.3717x; 1.0179x over previous
//
#include <hip/hip_runtime.h>

#define B_ 64
#define T_ 512
#define I_ 512
#define H_ 1024
#define FPAD 16       // pad flags to 64 B lines
#define TPS 16384     // shorts per team plane (16 rows x 1024 cols)
#define NWG 256       // 4 teams x 64 WGs
#define PAIRB 65536   // bytes per plane pair (hi 32 KB + lo 32 KB)
#define NDEPTH 4      // plane-ring depth (pair index = s & 3)
#define TEAMB (NDEPTH * PAIRB)

typedef __attribute__((ext_vector_type(8))) short bf16x8;
typedef __attribute__((ext_vector_type(4))) float f32x4;

static __device__ __forceinline__ short f2bf(float f) {
  unsigned u = __float_as_uint(f);
  unsigned r = (u + 0x7fffu + ((u >> 16) & 1u)) >> 16;  // RNE
  return (short)(unsigned short)r;
}
static __device__ __forceinline__ float bf2f(short s) {
  return __uint_as_float(((unsigned)(unsigned short)s) << 16);
}
static __device__ __forceinline__ bf16x8 pack8(float4 u, float4 v) {
  bf16x8 r;
  r[0] = f2bf(u.x); r[1] = f2bf(u.y); r[2] = f2bf(u.z); r[3] = f2bf(u.w);
  r[4] = f2bf(v.x); r[5] = f2bf(v.y); r[6] = f2bf(v.z); r[7] = f2bf(v.w);
  return r;
}

// ---------------------------------------------------------------------------
// Kernel 1 (unchanged): pre = x @ Wi^T + bi + bh, in-place into d_out.
// ---------------------------------------------------------------------------
#define PBK 32
#define PLDA 40

__global__ __launch_bounds__(256) void proj_gemm(
    const float* __restrict__ x, const float* __restrict__ Wi,
    const float* __restrict__ bi, const float* __restrict__ bh,
    float* __restrict__ out) {
  __shared__ short As[128 * PLDA];
  __shared__ short Bs[128 * PLDA];
  const int tid = threadIdx.x;
  const int m0 = (blockIdx.x >> 3) * 128;
  const int n0 = (blockIdx.x & 7) * 128;
  const int wave = tid >> 6, lane = tid & 63;
  const int wm = (wave & 1) * 64, wn = (wave >> 1) * 64;
  const int lm = lane & 15, lq = lane >> 4;

  f32x4 acc[4][4];
#pragma unroll
  for (int i = 0; i < 4; ++i)
#pragma unroll
    for (int j = 0; j < 4; ++j) {
      f32x4 z = {0.f, 0.f, 0.f, 0.f};
      acc[i][j] = z;
    }

  const int lrow = tid >> 1;
  const int lcol = (tid & 1) * 16;
  const float* xp = x + (size_t)(m0 + lrow) * I_ + lcol;
  const float* wp = Wi + (size_t)(n0 + lrow) * I_ + lcol;

  for (int k0 = 0; k0 < I_; k0 += PBK) {
    float4 a0 = *(const float4*)(xp + k0);
    float4 a1 = *(const float4*)(xp + k0 + 4);
    float4 a2 = *(const float4*)(xp + k0 + 8);
    float4 a3 = *(const float4*)(xp + k0 + 12);
    float4 b0 = *(const float4*)(wp + k0);
    float4 b1 = *(const float4*)(wp + k0 + 4);
    float4 b2 = *(const float4*)(wp + k0 + 8);
    float4 b3 = *(const float4*)(wp + k0 + 12);
    __syncthreads();
    *(bf16x8*)&As[lrow * PLDA + lcol] = pack8(a0, a1);
    *(bf16x8*)&As[lrow * PLDA + lcol + 8] = pack8(a2, a3);
    *(bf16x8*)&Bs[lrow * PLDA + lcol] = pack8(b0, b1);
    *(bf16x8*)&Bs[lrow * PLDA + lcol + 8] = pack8(b2, b3);
    __syncthreads();

    bf16x8 af[4], bfr[4];
#pragma unroll
    for (int i = 0; i < 4; ++i)
      af[i] = *(const bf16x8*)&As[(wm + i * 16 + lm) * PLDA + lq * 8];
#pragma unroll
    for (int j = 0; j < 4; ++j)
      bfr[j] = *(const bf16x8*)&Bs[(wn + j * 16 + lm) * PLDA + lq * 8];
#pragma unroll
    for (int i = 0; i < 4; ++i)
#pragma unroll
      for (int j = 0; j < 4; ++j)
        acc[i][j] = __builtin_amdgcn_mfma_f32_16x16x32_bf16(af[i], bfr[j],
                                                            acc[i][j], 0, 0, 0);
  }

  const int rb = m0 + wm + lq * 4;
  const int cb = n0 + wn + lm;
#pragma unroll
  for (int j = 0; j < 4; ++j) {
    const int n = cb + j * 16;
    const float bias = bi[n] + bh[n];
#pragma unroll
    for (int i = 0; i < 4; ++i) {
      const int m = rb + i * 16;
#pragma unroll
      for (int r = 0; r < 4; ++r)
        out[(size_t)(m + r) * H_ + n] = acc[i][j][r] + bias;
    }
  }
}

// ---------------------------------------------------------------------------
// Agent-scope (L3-coherent) helpers.
// ---------------------------------------------------------------------------
static __device__ __forceinline__ unsigned long long ld_a8(const void* p) {
  return __hip_atomic_load((const unsigned long long*)p, __ATOMIC_RELAXED,
                           __HIP_MEMORY_SCOPE_AGENT);
}
static __device__ __forceinline__ void st_a2(unsigned short* p,
                                             unsigned short v) {
  __hip_atomic_store(p, v, __ATOMIC_RELAXED, __HIP_MEMORY_SCOPE_AGENT);
}
static __device__ __forceinline__ void st_a8(unsigned long long* p,
                                             unsigned long long v) {
  __hip_atomic_store(p, v, __ATOMIC_RELAXED, __HIP_MEMORY_SCOPE_AGENT);
}
static __device__ __forceinline__ int ld_flag(const int* p) {
  return __hip_atomic_load(p, __ATOMIC_RELAXED, __HIP_MEMORY_SCOPE_AGENT);
}

union frag_u {
  unsigned long long q[2];
  bf16x8 v;
};

// ---------------------------------------------------------------------------
// Kernel 2 (R6 = R5 + coalesced exchange stores + depth-4 plane ring).
//
// Batch-team decomposition (R5, proven): 4 teams x 16 batch rows; WG w in a
// team owns output cols [16w,16w+16); 4 waves k-split 256 each, LDS-reduce.
//
// Plane ring: NDEPTH=4 pairs per team, pair index = s&3 (h_s lives in pair
// s&3; h_0 in pair 0). WG w's output region within a pair is CONTIGUOUS:
// hi bytes [512w, 512w+512), lo at +32768. Proof: short idx of h[r][c=16w+cl]
// = (c>>5)*512 + ((c>>3)&3)*128 + r*8 + (c&7) = 256w + (cl>>3)*128 + r*8 +
// (cl&7), and (cl>>3,r,cl&7) sweeps [0,256).
//
// Exchange store path (NEW): after the reduce, thread (r,cl) drops
// pk[r][cl] = hv | lv<<16 into LDS; wave 0 re-reads and issues TWO 64-lane
// fully-coalesced 8 B agent stores (lane l covers shorts [4l,4l+4): pk row
// (l>>1)&15, cols (l>>5)*8+(l&1)*4+k). 2 VMEM instrs / 16 full-line writes
// replace 512 scattered 2 B stores (partial-line L3 RMW + long drain).
//
// Sync semantics (R5-proven, unchanged): stores -> vmcnt(0) (wave 0 only
// now) -> __syncthreads -> flag[wg]=s.
//   read gate  (>= s-1, 16 producers): their h_{s-1} is at L3.
//   write gate (>= s-3, all 64 team WGs, polled pre-barrier): their reads of
//     pair (s-4)&3 = s&3 retired => overwrite safe. Depth-4 lets WGs skew up
//     to 3 steps -- stragglers no longer lockstep the team every step.
// Startup: h_0 zeros -> drain -> flag=0; pairs 1-3 are never read before
// written; 0xAA poison is negative so no gate false-passes.
// Deadlock-free: the WG at the global-min step has both gates satisfied.
// ---------------------------------------------------------------------------
__global__ __launch_bounds__(256, 1) void rnn_rec(
    const float* __restrict__ Wh, float* __restrict__ out,
    char* __restrict__ planes, int* __restrict__ flags) {
  const int tid = threadIdx.x;
  const int wg = blockIdx.x;
  const int team = wg >> 6;
  const int w = wg & 63;
  const int wv = tid >> 6;
  const int lane = tid & 63;
  const int lm = lane & 15, lq = lane >> 4;

  // --- B-frags: Wh[16w+lm][256wv + kbl*32 + lq*8 + j], rotated kbl=(w+i)&7
  bf16x8 Bh[8], Bl[8];
  {
    const float* wrow = Wh + (size_t)(16 * w + lm) * H_ + wv * 256 + lq * 8;
#pragma unroll
    for (int i = 0; i < 8; ++i) {
      const int kbl = (w + i) & 7;
      float4 w0 = *(const float4*)(wrow + kbl * 32);
      float4 w1 = *(const float4*)(wrow + kbl * 32 + 4);
      float wf[8] = {w0.x, w0.y, w0.z, w0.w, w1.x, w1.y, w1.z, w1.w};
      bf16x8 hi, lo;
#pragma unroll
      for (int j = 0; j < 8; ++j) {
        hi[j] = f2bf(wf[j]);
        lo[j] = f2bf(wf[j] - bf2f(hi[j]));
      }
      Bh[i] = hi;
      Bl[i] = lo;
    }
  }

  // --- thread owns (r = tid>>4, c = 16w + (tid&15)) ---
  const int r = tid >> 4;
  const int cl = tid & 15;
  const int c = 16 * w + cl;
  const int b = team * 16 + r;  // global batch row
  const int Sidx = 256 * w + (cl >> 3) * 128 + r * 8 + (cl & 7);

  char* tbase = planes + (size_t)team * TEAMB;
  const int* frd = flags + (team * 64 + 16 * wv + lm) * FPAD;  // read gate
  const int* fwr = flags + (team * 64 + lane) * FPAD;          // write gate
  const int fown = wg * FPAD;

  // --- startup: zero own h_0 slots (pair 0, hi+lo) -> drain -> sync -> flag=0
  {
    unsigned short* p0 = (unsigned short*)tbase;
    st_a2(p0 + Sidx, 0);
    st_a2(p0 + TPS + Sidx, 0);
  }
  asm volatile("s_waitcnt vmcnt(0)" ::: "memory");
  __syncthreads();
  if (tid == 0)
    __hip_atomic_store(&flags[fown], 0, __ATOMIC_RELAXED,
                       __HIP_MEMORY_SCOPE_AGENT);

  float* outH = out + (size_t)B_ * T_ * H_;
  __shared__ float red[4][64][4];   // 4 KB k-partial reduction buffer
  __shared__ unsigned pk[16][17];   // packed (hv|lv<<16), padded stride
  const int lp = (r >> 2) * 16 + cl;  // reduction source lane
  const int ri = r & 3;               // reduction source reg
  const int pr = (lane >> 1) & 15;               // wave-0 pack: pk row
  const int pc0 = (lane >> 5) * 8 + (lane & 1) * 4;  // pk col base

  for (int s = 1; s <= T_; ++s) {
    const int t = s - 1;
    const size_t oidx = (size_t)b * (T_ * H_) + (size_t)t * H_ + c;
    const float pre = out[oidx];  // L2-private; overlaps the read gate

    // read gate: my 16 producers have h_{s-1} at L3 (flag posts AFTER drain)
    const int need = s - 1;
    for (;;) {
      const int f = ld_flag(frd);
      if (__all(f >= need)) break;
      __builtin_amdgcn_s_sleep(1);
    }

    // all 8 A-blocks (hi+lo), issued back-to-back post-gate; no refills
    const char* src = tbase + (size_t)((s - 1) & 3) * PAIRB;
    unsigned long long q[8][4];
#pragma unroll
    for (int i = 0; i < 8; ++i) {
      const int kb = 8 * wv + ((w + i) & 7);
      const char* p = src + kb * 1024 + lane * 16;
      q[i][0] = ld_a8(p);
      q[i][1] = ld_a8(p + 8);
      q[i][2] = ld_a8(p + 32768);      // lo plane
      q[i][3] = ld_a8(p + 32768 + 8);
    }

    const f32x4 z = {0.f, 0.f, 0.f, 0.f};
    f32x4 c0 = z, c1 = z, c2 = z;
#pragma unroll
    for (int i = 0; i < 8; ++i) {
      frag_u ah, al;
      ah.q[0] = q[i][0];
      ah.q[1] = q[i][1];
      al.q[0] = q[i][2];
      al.q[1] = q[i][3];
      c0 = __builtin_amdgcn_mfma_f32_16x16x32_bf16(ah.v, Bh[i], c0, 0, 0, 0);
      c1 = __builtin_amdgcn_mfma_f32_16x16x32_bf16(ah.v, Bl[i], c1, 0, 0, 0);
      c2 = __builtin_amdgcn_mfma_f32_16x16x32_bf16(al.v, Bh[i], c2, 0, 0, 0);
    }
    const f32x4 rs = c0 + c1 + c2;

    // LDS partial write, then write gate (overlaps barrier convergence):
    // all team flags >= s-3 => pair (s&3) readers (step s-3) retired.
    *(f32x4*)&red[wv][lane][0] = rs;
    const int need2 = s - 3;
    for (;;) {
      const int f = ld_flag(fwr);
      if (__all(f >= need2)) break;
      __builtin_amdgcn_s_sleep(1);
    }
    __syncthreads();
    const float sum = red[0][lp][ri] + red[1][lp][ri] + red[2][lp][ri] +
                      red[3][lp][ri];
    float v = pre + sum;
    v = v > 0.f ? v : 0.f;

    // pack (hv,lv) to LDS; out-writes ride here (off the critical chain)
    const short hv = f2bf(v);
    const short lv = f2bf(v - bf2f(hv));
    pk[r][cl] = (unsigned)(unsigned short)hv | ((unsigned)(unsigned short)lv << 16);
    out[oidx] = v;
    if (s == T_) outH[(size_t)b * H_ + c] = v;
    __syncthreads();

    // wave 0: two fully-coalesced 64-lane 8 B agent stores (hi, lo), drain
    if (wv == 0) {
      unsigned long long hq = 0, lq2 = 0;
#pragma unroll
      for (int k = 0; k < 4; ++k) {
        const unsigned u = pk[pr][pc0 + k];
        hq |= ((unsigned long long)(u & 0xffffu)) << (16 * k);
        lq2 |= ((unsigned long long)(u >> 16)) << (16 * k);
      }
      char* dst = tbase + (size_t)(s & 3) * PAIRB;
      st_a8((unsigned long long*)(dst + 512 * w + 8 * lane), hq);
      st_a8((unsigned long long*)(dst + 32768 + 512 * w + 8 * lane), lq2);
      asm volatile("s_waitcnt vmcnt(0)" ::: "memory");
    }
    __syncthreads();
    if (tid == 0)
      __hip_atomic_store(&flags[fown], s, __ATOMIC_RELAXED,
                         __HIP_MEMORY_SCOPE_AGENT);
  }
}

// ---------------------------------------------------------------------------
extern "C" void kernel_launch(void* const* d_in, const int* in_sizes, int n_in,
                              void* d_out, int out_size, void* d_ws,
                              size_t ws_size, hipStream_t stream) {
  const float* x = (const float*)d_in[0];   // [B,T,I]
  const float* Wi = (const float*)d_in[1];  // [H,I]
  const float* bi = (const float*)d_in[2];  // [H]
  const float* Wh = (const float*)d_in[3];  // [H,H]
  const float* bh = (const float*)d_in[4];  // [H]
  float* out = (float*)d_out;

  int* flags = (int*)d_ws;                       // 256 x 64 B = 16 KB
  char* planes = (char*)d_ws + 32768;            // 4 teams x 256 KB = 1 MB

  proj_gemm<<<2048, 256, 0, stream>>>(x, Wi, bi, bh, out);
  rnn_rec<<<NWG, 256, 0, stream>>>(Wh, out, planes, flags);
}

// Round 7
// 2522.184 us; speedup vs baseline: 4.7211x; 1.0799x over previous
//
#include <hip/hip_runtime.h>

#define B_ 64
#define T_ 512
#define I_ 512
#define H_ 1024
#define FPAD 16       // pad flags to 64 B lines
#define TPS 16384     // shorts per team plane (16 rows x 1024 cols)
#define NWG 256       // 4 teams x 64 WGs
#define PAIRB 65536   // bytes per plane pair (hi 32 KB + lo 32 KB)
#define NDEPTH 4      // plane-ring depth (pair index = s & 3)
#define TEAMB (NDEPTH * PAIRB)
#define TAGM 0x8000800080008000ULL

typedef __attribute__((ext_vector_type(8))) short bf16x8;
typedef __attribute__((ext_vector_type(4))) float f32x4;

static __device__ __forceinline__ short f2bf(float f) {
  unsigned u = __float_as_uint(f);
  unsigned r = (u + 0x7fffu + ((u >> 16) & 1u)) >> 16;  // RNE
  return (short)(unsigned short)r;
}
static __device__ __forceinline__ float bf2f(short s) {
  return __uint_as_float(((unsigned)(unsigned short)s) << 16);
}
static __device__ __forceinline__ bf16x8 pack8(float4 u, float4 v) {
  bf16x8 r;
  r[0] = f2bf(u.x); r[1] = f2bf(u.y); r[2] = f2bf(u.z); r[3] = f2bf(u.w);
  r[4] = f2bf(v.x); r[5] = f2bf(v.y); r[6] = f2bf(v.z); r[7] = f2bf(v.w);
  return r;
}

// ---------------------------------------------------------------------------
// Kernel 1 (unchanged): pre = x @ Wi^T + bi + bh, in-place into d_out.
// ---------------------------------------------------------------------------
#define PBK 32
#define PLDA 40

__global__ __launch_bounds__(256) void proj_gemm(
    const float* __restrict__ x, const float* __restrict__ Wi,
    const float* __restrict__ bi, const float* __restrict__ bh,
    float* __restrict__ out) {
  __shared__ short As[128 * PLDA];
  __shared__ short Bs[128 * PLDA];
  const int tid = threadIdx.x;
  const int m0 = (blockIdx.x >> 3) * 128;
  const int n0 = (blockIdx.x & 7) * 128;
  const int wave = tid >> 6, lane = tid & 63;
  const int wm = (wave & 1) * 64, wn = (wave >> 1) * 64;
  const int lm = lane & 15, lq = lane >> 4;

  f32x4 acc[4][4];
#pragma unroll
  for (int i = 0; i < 4; ++i)
#pragma unroll
    for (int j = 0; j < 4; ++j) {
      f32x4 z = {0.f, 0.f, 0.f, 0.f};
      acc[i][j] = z;
    }

  const int lrow = tid >> 1;
  const int lcol = (tid & 1) * 16;
  const float* xp = x + (size_t)(m0 + lrow) * I_ + lcol;
  const float* wp = Wi + (size_t)(n0 + lrow) * I_ + lcol;

  for (int k0 = 0; k0 < I_; k0 += PBK) {
    float4 a0 = *(const float4*)(xp + k0);
    float4 a1 = *(const float4*)(xp + k0 + 4);
    float4 a2 = *(const float4*)(xp + k0 + 8);
    float4 a3 = *(const float4*)(xp + k0 + 12);
    float4 b0 = *(const float4*)(wp + k0);
    float4 b1 = *(const float4*)(wp + k0 + 4);
    float4 b2 = *(const float4*)(wp + k0 + 8);
    float4 b3 = *(const float4*)(wp + k0 + 12);
    __syncthreads();
    *(bf16x8*)&As[lrow * PLDA + lcol] = pack8(a0, a1);
    *(bf16x8*)&As[lrow * PLDA + lcol + 8] = pack8(a2, a3);
    *(bf16x8*)&Bs[lrow * PLDA + lcol] = pack8(b0, b1);
    *(bf16x8*)&Bs[lrow * PLDA + lcol + 8] = pack8(b2, b3);
    __syncthreads();

    bf16x8 af[4], bfr[4];
#pragma unroll
    for (int i = 0; i < 4; ++i)
      af[i] = *(const bf16x8*)&As[(wm + i * 16 + lm) * PLDA + lq * 8];
#pragma unroll
    for (int j = 0; j < 4; ++j)
      bfr[j] = *(const bf16x8*)&Bs[(wn + j * 16 + lm) * PLDA + lq * 8];
#pragma unroll
    for (int i = 0; i < 4; ++i)
#pragma unroll
      for (int j = 0; j < 4; ++j)
        acc[i][j] = __builtin_amdgcn_mfma_f32_16x16x32_bf16(af[i], bfr[j],
                                                            acc[i][j], 0, 0, 0);
  }

  const int rb = m0 + wm + lq * 4;
  const int cb = n0 + wn + lm;
#pragma unroll
  for (int j = 0; j < 4; ++j) {
    const int n = cb + j * 16;
    const float bias = bi[n] + bh[n];
#pragma unroll
    for (int i = 0; i < 4; ++i) {
      const int m = rb + i * 16;
#pragma unroll
      for (int r = 0; r < 4; ++r)
        out[(size_t)(m + r) * H_ + n] = acc[i][j][r] + bias;
    }
  }
}

// ---------------------------------------------------------------------------
// Agent-scope (L3-coherent) helpers.
// ---------------------------------------------------------------------------
static __device__ __forceinline__ unsigned long long ld_a8(const void* p) {
  return __hip_atomic_load((const unsigned long long*)p, __ATOMIC_RELAXED,
                           __HIP_MEMORY_SCOPE_AGENT);
}
static __device__ __forceinline__ void st_a2(unsigned short* p,
                                             unsigned short v) {
  __hip_atomic_store(p, v, __ATOMIC_RELAXED, __HIP_MEMORY_SCOPE_AGENT);
}
static __device__ __forceinline__ void st_a8(unsigned long long* p,
                                             unsigned long long v) {
  __hip_atomic_store(p, v, __ATOMIC_RELAXED, __HIP_MEMORY_SCOPE_AGENT);
}
static __device__ __forceinline__ int ld_flag(const int* p) {
  return __hip_atomic_load(p, __ATOMIC_RELAXED, __HIP_MEMORY_SCOPE_AGENT);
}

union frag_u {
  unsigned long long q[2];
  bf16x8 v;
};

// ---------------------------------------------------------------------------
// Kernel 2 (R7 = R6 teams + FLAGLESS READ PATH via batched self-tag polls).
//
// Teams (R5/R6, proven): 4 teams x 16 batch rows; WG w owns output cols
// [16w,16w+16); 4 waves k-split 256 each, LDS-reduce. Plane ring NDEPTH=4,
// pair = s&3; WG w's output region contiguous (hi [512w,512w+512), lo +32K).
//
// READ PATH (new): no read flag. Every stored short carries a generation tag
// in its sign bit (ReLU => h>=0; hi=TRUNC(v) => lo=v-hi>=0). tag(s)=(s>>2)&1,
// so consecutive writers of a pair alternate tags; tag=1 steps store NEGATED
// values and the consumer computes v = pre - sum (tag strip is free).
// Consumer issues all 8 blocks' loads, then a BATCHED poll: check all blocks'
// tags, reissue ALL stale blocks in parallel, sleep, repeat. Each round = one
// L3 RT for the whole batch (this was R1/R3's fatal flaw: their retry was
// per-block serialized inside the MFMA loop). The poll load IS the data load.
//
// WRITE PATH: producer issues tagged h stores with NO drain -- landing is
// detected by consumers' tag polls. Write-after-write to the same address is
// same-lane program-ordered; 4-step spacing makes it moot.
//
// FLAGS (kept, write gate only, drain-free): tid0 posts flag[wg]=s right
// after the reduce barrier -- at that point ALL waves' step-s loads have
// retired (data dep through MFMA -> red[] -> barrier), which is exactly what
// ping-pong safety needs. flag >= s-3 for all team WGs => pair (s&3) readers
// (step s-3) are done => overwrite safe. Gate is monotone so it's polled
// early (overlapping the data poll). Tag aliasing needs skew >= 4: the gate
// bounds skew <= 3.
// Startup: zero h_0 (tag 0). 0xAA poison has sign 1 => rejected by TR=0 tag
// checks; flags init 0 (poison negative => write gate blocks, safe).
// Deadlock-free: global-min-step WG's producers are all >= its step (stores
// issued, eventually visible), and its write gate is trivially satisfied.
// ---------------------------------------------------------------------------
__global__ __launch_bounds__(256, 1) void rnn_rec(
    const float* __restrict__ Wh, float* __restrict__ out,
    char* __restrict__ planes, int* __restrict__ flags) {
  const int tid = threadIdx.x;
  const int wg = blockIdx.x;
  const int team = wg >> 6;
  const int w = wg & 63;
  const int wv = tid >> 6;
  const int lane = tid & 63;
  const int lm = lane & 15, lq = lane >> 4;

  // --- B-frags: Wh[16w+lm][256wv + kbl*32 + lq*8 + j], rotated kbl=(w+i)&7
  bf16x8 Bh[8], Bl[8];
  {
    const float* wrow = Wh + (size_t)(16 * w + lm) * H_ + wv * 256 + lq * 8;
#pragma unroll
    for (int i = 0; i < 8; ++i) {
      const int kbl = (w + i) & 7;
      float4 w0 = *(const float4*)(wrow + kbl * 32);
      float4 w1 = *(const float4*)(wrow + kbl * 32 + 4);
      float wf[8] = {w0.x, w0.y, w0.z, w0.w, w1.x, w1.y, w1.z, w1.w};
      bf16x8 hi, lo;
#pragma unroll
      for (int j = 0; j < 8; ++j) {
        hi[j] = f2bf(wf[j]);
        lo[j] = f2bf(wf[j] - bf2f(hi[j]));
      }
      Bh[i] = hi;
      Bl[i] = lo;
    }
  }

  // --- thread owns (r = tid>>4, c = 16w + (tid&15)) ---
  const int r = tid >> 4;
  const int cl = tid & 15;
  const int c = 16 * w + cl;
  const int b = team * 16 + r;  // global batch row
  const int Sidx = 256 * w + (cl >> 3) * 128 + r * 8 + (cl & 7);

  char* tbase = planes + (size_t)team * TEAMB;
  const int* fwr = flags + (team * 64 + lane) * FPAD;  // write gate
  const int fown = wg * FPAD;

  // --- startup: zero own h_0 slots (pair 0, tag 0); flag=0. No drains needed:
  // consumers' tag polls absorb landing latency; poison blocks gates safely.
  {
    unsigned short* p0 = (unsigned short*)tbase;
    st_a2(p0 + Sidx, 0);
    st_a2(p0 + TPS + Sidx, 0);
  }
  __syncthreads();
  if (tid == 0)
    __hip_atomic_store(&flags[fown], 0, __ATOMIC_RELAXED,
                       __HIP_MEMORY_SCOPE_AGENT);

  float* outH = out + (size_t)B_ * T_ * H_;
  __shared__ float red[4][64][4];   // 4 KB k-partial reduction buffer
  __shared__ unsigned pk[16][17];   // packed (hv|lv<<16), padded stride
  const int lp = (r >> 2) * 16 + cl;  // reduction source lane
  const int ri = r & 3;               // reduction source reg
  const int pr = (lane >> 1) & 15;               // wave-0 pack: pk row
  const int pc0 = (lane >> 5) * 8 + (lane & 1) * 4;  // pk col base

  for (int s = 1; s <= T_; ++s) {
    const int t = s - 1;
    const int TR = ((s - 1) >> 2) & 1;               // expected tag of h_{s-1}
    const unsigned short flip = (unsigned short)(((s >> 2) & 1) << 15);
    const size_t oidx = (size_t)b * (T_ * H_) + (size_t)t * H_ + c;
    const float pre = out[oidx];  // overlaps the data poll

    // issue all 8 A-blocks (hi+lo)
    const char* src = tbase + (size_t)((s - 1) & 3) * PAIRB;
    unsigned long long q[8][4];
#pragma unroll
    for (int i = 0; i < 8; ++i) {
      const int kb = 8 * wv + ((w + i) & 7);
      const char* p = src + kb * 1024 + lane * 16;
      q[i][0] = ld_a8(p);
      q[i][1] = ld_a8(p + 8);
      q[i][2] = ld_a8(p + 32768);      // lo plane
      q[i][3] = ld_a8(p + 32768 + 8);
    }

    // write gate (monotone, checked early; overlaps the data RT):
    // all team flags >= s-3 => pair (s&3) readers (step s-3) retired.
    const int need2 = s - 3;
    for (;;) {
      const int f = ld_flag(fwr);
      if (__all(f >= need2)) break;
      __builtin_amdgcn_s_sleep(1);
    }

    // batched self-tag poll: reissue ALL stale blocks per round (1 RT/round)
    {
      unsigned pend = 0xffu;
      for (;;) {
        unsigned np = 0;
#pragma unroll
        for (int i = 0; i < 8; ++i)
          if (pend & (1u << i)) {
            bool ok;
            if (TR) {
              const unsigned long long y =
                  q[i][0] & q[i][1] & q[i][2] & q[i][3];
              ok = (y & TAGM) == TAGM;
            } else {
              const unsigned long long x =
                  q[i][0] | q[i][1] | q[i][2] | q[i][3];
              ok = (x & TAGM) == 0ULL;
            }
            if (!__all(ok)) np |= 1u << i;
          }
        pend = np;
        if (!pend) break;
        __builtin_amdgcn_s_sleep(1);
#pragma unroll
        for (int i = 0; i < 8; ++i)
          if (pend & (1u << i)) {
            const int kb = 8 * wv + ((w + i) & 7);
            const char* p = src + kb * 1024 + lane * 16;
            q[i][0] = ld_a8(p);
            q[i][1] = ld_a8(p + 8);
            q[i][2] = ld_a8(p + 32768);
            q[i][3] = ld_a8(p + 32768 + 8);
          }
      }
    }

    const f32x4 z = {0.f, 0.f, 0.f, 0.f};
    f32x4 c0 = z, c1 = z, c2 = z;
#pragma unroll
    for (int i = 0; i < 8; ++i) {
      frag_u ah, al;
      ah.q[0] = q[i][0];
      ah.q[1] = q[i][1];
      al.q[0] = q[i][2];
      al.q[1] = q[i][3];
      c0 = __builtin_amdgcn_mfma_f32_16x16x32_bf16(ah.v, Bh[i], c0, 0, 0, 0);
      c1 = __builtin_amdgcn_mfma_f32_16x16x32_bf16(ah.v, Bl[i], c1, 0, 0, 0);
      c2 = __builtin_amdgcn_mfma_f32_16x16x32_bf16(al.v, Bh[i], c2, 0, 0, 0);
    }
    const f32x4 rs = c0 + c1 + c2;

    *(f32x4*)&red[wv][lane][0] = rs;
    __syncthreads();
    // flag=s here proves: all waves' step-s loads retired (write-gate basis).
    // Posted drain-free, off the critical path.
    if (tid == 0)
      __hip_atomic_store(&flags[fown], s, __ATOMIC_RELAXED,
                         __HIP_MEMORY_SCOPE_AGENT);
    const float sum = red[0][lp][ri] + red[1][lp][ri] + red[2][lp][ri] +
                      red[3][lp][ri];
    float v = pre + (TR ? -sum : sum);  // TR=1 data was stored negated
    v = v > 0.f ? v : 0.f;

    // pack tagged (hv,lv): hi = TRUNC => lo >= 0 => both signs free for tag
    const unsigned short hv =
        (unsigned short)(__float_as_uint(v) >> 16);          // trunc, >= 0
    const float hf = __uint_as_float((unsigned)hv << 16);
    const unsigned short lv = (unsigned short)f2bf(v - hf);  // RNE, >= 0
    pk[r][cl] = (unsigned)(unsigned short)(hv ^ flip) |
                ((unsigned)(unsigned short)(lv ^ flip) << 16);
    __syncthreads();

    // wave 0: two fully-coalesced 64-lane 8 B tagged stores, NO drain --
    // landing is detected by consumers' tag polls.
    if (wv == 0) {
      unsigned long long hq = 0, lq2 = 0;
#pragma unroll
      for (int k = 0; k < 4; ++k) {
        const unsigned u = pk[pr][pc0 + k];
        hq |= ((unsigned long long)(u & 0xffffu)) << (16 * k);
        lq2 |= ((unsigned long long)(u >> 16)) << (16 * k);
      }
      char* dst = tbase + (size_t)(s & 3) * PAIRB;
      st_a8((unsigned long long*)(dst + 512 * w + 8 * lane), hq);
      st_a8((unsigned long long*)(dst + 32768 + 512 * w + 8 * lane), lq2);
    }
    // out writes off the critical chain
    out[oidx] = v;
    if (s == T_) outH[(size_t)b * H_ + c] = v;
  }
}

// ---------------------------------------------------------------------------
extern "C" void kernel_launch(void* const* d_in, const int* in_sizes, int n_in,
                              void* d_out, int out_size, void* d_ws,
                              size_t ws_size, hipStream_t stream) {
  const float* x = (const float*)d_in[0];   // [B,T,I]
  const float* Wi = (const float*)d_in[1];  // [H,I]
  const float* bi = (const float*)d_in[2];  // [H]
  const float* Wh = (const float*)d_in[3];  // [H,H]
  const float* bh = (const float*)d_in[4];  // [H]
  float* out = (float*)d_out;

  int* flags = (int*)d_ws;                       // 256 x 64 B = 16 KB
  char* planes = (char*)d_ws + 32768;            // 4 teams x 256 KB = 1 MB

  proj_gemm<<<2048, 256, 0, stream>>>(x, Wi, bi, bh, out);
  rnn_rec<<<NWG, 256, 0, stream>>>(Wh, out, planes, flags);
}

// Round 8
// 2381.289 us; speedup vs baseline: 5.0005x; 1.0592x over previous
//
#include <hip/hip_runtime.h>

#define B_ 64
#define T_ 512
#define I_ 512
#define H_ 1024
#define FPAD 16       // pad flags to 64 B lines
#define TPS 16384     // shorts per team plane (16 rows x 1024 cols)
#define NWG 256       // 4 teams x 64 WGs
#define PAIRB 65536   // bytes per plane pair (hi 32 KB + lo 32 KB)
#define NDEPTH 4      // plane-ring depth (pair index = s & 3)
#define TEAMB (NDEPTH * PAIRB)
#define TAGM 0x8000800080008000ULL

typedef __attribute__((ext_vector_type(8))) short bf16x8;
typedef __attribute__((ext_vector_type(4))) float f32x4;

static __device__ __forceinline__ short f2bf(float f) {
  unsigned u = __float_as_uint(f);
  unsigned r = (u + 0x7fffu + ((u >> 16) & 1u)) >> 16;  // RNE
  return (short)(unsigned short)r;
}
static __device__ __forceinline__ float bf2f(short s) {
  return __uint_as_float(((unsigned)(unsigned short)s) << 16);
}
static __device__ __forceinline__ bf16x8 pack8(float4 u, float4 v) {
  bf16x8 r;
  r[0] = f2bf(u.x); r[1] = f2bf(u.y); r[2] = f2bf(u.z); r[3] = f2bf(u.w);
  r[4] = f2bf(v.x); r[5] = f2bf(v.y); r[6] = f2bf(v.z); r[7] = f2bf(v.w);
  return r;
}

// ---------------------------------------------------------------------------
// Kernel 1 (unchanged): pre = x @ Wi^T + bi + bh, in-place into d_out.
// ---------------------------------------------------------------------------
#define PBK 32
#define PLDA 40

__global__ __launch_bounds__(256) void proj_gemm(
    const float* __restrict__ x, const float* __restrict__ Wi,
    const float* __restrict__ bi, const float* __restrict__ bh,
    float* __restrict__ out) {
  __shared__ short As[128 * PLDA];
  __shared__ short Bs[128 * PLDA];
  const int tid = threadIdx.x;
  const int m0 = (blockIdx.x >> 3) * 128;
  const int n0 = (blockIdx.x & 7) * 128;
  const int wave = tid >> 6, lane = tid & 63;
  const int wm = (wave & 1) * 64, wn = (wave >> 1) * 64;
  const int lm = lane & 15, lq = lane >> 4;

  f32x4 acc[4][4];
#pragma unroll
  for (int i = 0; i < 4; ++i)
#pragma unroll
    for (int j = 0; j < 4; ++j) {
      f32x4 z = {0.f, 0.f, 0.f, 0.f};
      acc[i][j] = z;
    }

  const int lrow = tid >> 1;
  const int lcol = (tid & 1) * 16;
  const float* xp = x + (size_t)(m0 + lrow) * I_ + lcol;
  const float* wp = Wi + (size_t)(n0 + lrow) * I_ + lcol;

  for (int k0 = 0; k0 < I_; k0 += PBK) {
    float4 a0 = *(const float4*)(xp + k0);
    float4 a1 = *(const float4*)(xp + k0 + 4);
    float4 a2 = *(const float4*)(xp + k0 + 8);
    float4 a3 = *(const float4*)(xp + k0 + 12);
    float4 b0 = *(const float4*)(wp + k0);
    float4 b1 = *(const float4*)(wp + k0 + 4);
    float4 b2 = *(const float4*)(wp + k0 + 8);
    float4 b3 = *(const float4*)(wp + k0 + 12);
    __syncthreads();
    *(bf16x8*)&As[lrow * PLDA + lcol] = pack8(a0, a1);
    *(bf16x8*)&As[lrow * PLDA + lcol + 8] = pack8(a2, a3);
    *(bf16x8*)&Bs[lrow * PLDA + lcol] = pack8(b0, b1);
    *(bf16x8*)&Bs[lrow * PLDA + lcol + 8] = pack8(b2, b3);
    __syncthreads();

    bf16x8 af[4], bfr[4];
#pragma unroll
    for (int i = 0; i < 4; ++i)
      af[i] = *(const bf16x8*)&As[(wm + i * 16 + lm) * PLDA + lq * 8];
#pragma unroll
    for (int j = 0; j < 4; ++j)
      bfr[j] = *(const bf16x8*)&Bs[(wn + j * 16 + lm) * PLDA + lq * 8];
#pragma unroll
    for (int i = 0; i < 4; ++i)
#pragma unroll
      for (int j = 0; j < 4; ++j)
        acc[i][j] = __builtin_amdgcn_mfma_f32_16x16x32_bf16(af[i], bfr[j],
                                                            acc[i][j], 0, 0, 0);
  }

  const int rb = m0 + wm + lq * 4;
  const int cb = n0 + wn + lm;
#pragma unroll
  for (int j = 0; j < 4; ++j) {
    const int n = cb + j * 16;
    const float bias = bi[n] + bh[n];
#pragma unroll
    for (int i = 0; i < 4; ++i) {
      const int m = rb + i * 16;
#pragma unroll
      for (int r = 0; r < 4; ++r)
        out[(size_t)(m + r) * H_ + n] = acc[i][j][r] + bias;
    }
  }
}

// ---------------------------------------------------------------------------
// Agent-scope (L3-coherent) helpers.
// ---------------------------------------------------------------------------
static __device__ __forceinline__ unsigned long long ld_a8(const void* p) {
  return __hip_atomic_load((const unsigned long long*)p, __ATOMIC_RELAXED,
                           __HIP_MEMORY_SCOPE_AGENT);
}
static __device__ __forceinline__ void st_a2(unsigned short* p,
                                             unsigned short v) {
  __hip_atomic_store(p, v, __ATOMIC_RELAXED, __HIP_MEMORY_SCOPE_AGENT);
}
static __device__ __forceinline__ void st_a8(unsigned long long* p,
                                             unsigned long long v) {
  __hip_atomic_store(p, v, __ATOMIC_RELAXED, __HIP_MEMORY_SCOPE_AGENT);
}
static __device__ __forceinline__ int ld_flag(const int* p) {
  return __hip_atomic_load(p, __ATOMIC_RELAXED, __HIP_MEMORY_SCOPE_AGENT);
}

union frag_u {
  unsigned long long q[2];
  bf16x8 v;
};

// ---------------------------------------------------------------------------
// Kernel 2 (R8 = R7 + SENTINEL POLLING -- decongest L3).
//
// R7 post-mortem: the batched full-data poll re-issued 512 B/wave/round
// (~8 MB of L3 reads per round across 1024 waves, each hot line requested
// ~64x/round) -> the polls themselves congested L3, stretching every RT;
// VALUBusy 12% was the tag-check loops. Fix: poll 8 B sentinels, fetch once.
//
// READ PATH: (1) sentinel spin -- lane l samples ONE 8 B word: block i=l>>3
// (kb = 8wv + ((w+i)&7)), slot (l&7)*128 within the 1 KB hi-row. One __all
// covers all 8 blocks; rounds cost 64 B/wave. (2) when sentinels carry the
// expected generation tag, issue the full 32-load fetch ONCE; (3) R7's
// batched pend-mask tag verify stays as the correctness backstop (sentinels
// sample 8/64 slots; tags still validate every 16 B fragment; partial-landing
// races -> rare batched retry). The write-gate poll overlaps the fetch RT.
//
// Everything else is R7 verbatim: sign-bit generation tags (ReLU => h>=0,
// hi=TRUNC => lo>=0; tag(s)=(s>>2)&1; tag=1 steps store negated values and
// consumers compute v = pre - sum), NDEPTH=4 ring with drain-free write-gate
// flags posted after the reduce barrier (proves step-s loads retired; bounds
// skew <= 3 so tag aliasing at distance 4 is unreachable), teams of 16 batch
// rows x 64 WGs, 4-wave k-split + LDS reduce, wave-0 coalesced tagged stores
// with NO drain, h_0 zeros (tag 0) + flag=0 startup (0xAA poison: sign=1 is
// rejected by TR=0 tag checks; negative flags block the write gate safely).
// Deadlock-free: global-min-step WG's producers have issued their stores
// (eventually visible -> sentinels pass) and its write gate is satisfied.
// ---------------------------------------------------------------------------
__global__ __launch_bounds__(256, 1) void rnn_rec(
    const float* __restrict__ Wh, float* __restrict__ out,
    char* __restrict__ planes, int* __restrict__ flags) {
  const int tid = threadIdx.x;
  const int wg = blockIdx.x;
  const int team = wg >> 6;
  const int w = wg & 63;
  const int wv = tid >> 6;
  const int lane = tid & 63;
  const int lm = lane & 15, lq = lane >> 4;

  // --- B-frags: Wh[16w+lm][256wv + kbl*32 + lq*8 + j], rotated kbl=(w+i)&7
  bf16x8 Bh[8], Bl[8];
  {
    const float* wrow = Wh + (size_t)(16 * w + lm) * H_ + wv * 256 + lq * 8;
#pragma unroll
    for (int i = 0; i < 8; ++i) {
      const int kbl = (w + i) & 7;
      float4 w0 = *(const float4*)(wrow + kbl * 32);
      float4 w1 = *(const float4*)(wrow + kbl * 32 + 4);
      float wf[8] = {w0.x, w0.y, w0.z, w0.w, w1.x, w1.y, w1.z, w1.w};
      bf16x8 hi, lo;
#pragma unroll
      for (int j = 0; j < 8; ++j) {
        hi[j] = f2bf(wf[j]);
        lo[j] = f2bf(wf[j] - bf2f(hi[j]));
      }
      Bh[i] = hi;
      Bl[i] = lo;
    }
  }

  // --- thread owns (r = tid>>4, c = 16w + (tid&15)) ---
  const int r = tid >> 4;
  const int cl = tid & 15;
  const int c = 16 * w + cl;
  const int b = team * 16 + r;  // global batch row
  const int Sidx = 256 * w + (cl >> 3) * 128 + r * 8 + (cl & 7);

  char* tbase = planes + (size_t)team * TEAMB;
  const int* fwr = flags + (team * 64 + lane) * FPAD;  // write gate
  const int fown = wg * FPAD;

  // --- sentinel constants: lane l samples block si=l>>3, slot (l&7)*128 ---
  const int si = lane >> 3;
  const int skb = 8 * wv + ((w + si) & 7);
  const int soff = skb * 1024 + (lane & 7) * 128;

  // --- startup: zero own h_0 slots (pair 0, tag 0); flag=0. No drains needed:
  // consumers' tag polls absorb landing latency; poison blocks gates safely.
  {
    unsigned short* p0 = (unsigned short*)tbase;
    st_a2(p0 + Sidx, 0);
    st_a2(p0 + TPS + Sidx, 0);
  }
  __syncthreads();
  if (tid == 0)
    __hip_atomic_store(&flags[fown], 0, __ATOMIC_RELAXED,
                       __HIP_MEMORY_SCOPE_AGENT);

  float* outH = out + (size_t)B_ * T_ * H_;
  __shared__ float red[4][64][4];   // 4 KB k-partial reduction buffer
  __shared__ unsigned pk[16][17];   // packed (hv|lv<<16), padded stride
  const int lp = (r >> 2) * 16 + cl;  // reduction source lane
  const int ri = r & 3;               // reduction source reg
  const int pr = (lane >> 1) & 15;               // wave-0 pack: pk row
  const int pc0 = (lane >> 5) * 8 + (lane & 1) * 4;  // pk col base

  for (int s = 1; s <= T_; ++s) {
    const int t = s - 1;
    const int TR = ((s - 1) >> 2) & 1;               // expected tag of h_{s-1}
    const unsigned short flip = (unsigned short)(((s >> 2) & 1) << 15);
    const size_t oidx = (size_t)b * (T_ * H_) + (size_t)t * H_ + c;
    const float pre = out[oidx];  // issued early; consumed at v-compute

    const char* src = tbase + (size_t)((s - 1) & 3) * PAIRB;

    // (1) sentinel spin: 8 B/lane samples one slot of one block; one __all
    // covers all 8 blocks of this wave. 64 B/wave/round -- L3 stays cool.
    for (;;) {
      const unsigned long long x = ld_a8(src + soff);
      const bool ok = TR ? ((x & TAGM) == TAGM) : ((x & TAGM) == 0ULL);
      if (__all(ok)) break;
      __builtin_amdgcn_s_sleep(1);
    }

    // (2) full fetch ONCE (sentinels say the generation has landed)
    unsigned long long q[8][4];
#pragma unroll
    for (int i = 0; i < 8; ++i) {
      const int kb = 8 * wv + ((w + i) & 7);
      const char* p = src + kb * 1024 + lane * 16;
      q[i][0] = ld_a8(p);
      q[i][1] = ld_a8(p + 8);
      q[i][2] = ld_a8(p + 32768);      // lo plane
      q[i][3] = ld_a8(p + 32768 + 8);
    }

    // write gate (monotone; overlaps the fetch RT):
    // all team flags >= s-3 => pair (s&3) readers (step s-3) retired.
    const int need2 = s - 3;
    for (;;) {
      const int f = ld_flag(fwr);
      if (__all(f >= need2)) break;
      __builtin_amdgcn_s_sleep(1);
    }

    // (3) backstop: batched per-16B tag verify; reissue stale blocks in
    // parallel (rare -- only partial-landing races slip past sentinels)
    {
      unsigned pend = 0xffu;
      for (;;) {
        unsigned np = 0;
#pragma unroll
        for (int i = 0; i < 8; ++i)
          if (pend & (1u << i)) {
            bool ok;
            if (TR) {
              const unsigned long long y =
                  q[i][0] & q[i][1] & q[i][2] & q[i][3];
              ok = (y & TAGM) == TAGM;
            } else {
              const unsigned long long x =
                  q[i][0] | q[i][1] | q[i][2] | q[i][3];
              ok = (x & TAGM) == 0ULL;
            }
            if (!__all(ok)) np |= 1u << i;
          }
        pend = np;
        if (!pend) break;
        __builtin_amdgcn_s_sleep(1);
#pragma unroll
        for (int i = 0; i < 8; ++i)
          if (pend & (1u << i)) {
            const int kb = 8 * wv + ((w + i) & 7);
            const char* p = src + kb * 1024 + lane * 16;
            q[i][0] = ld_a8(p);
            q[i][1] = ld_a8(p + 8);
            q[i][2] = ld_a8(p + 32768);
            q[i][3] = ld_a8(p + 32768 + 8);
          }
      }
    }

    const f32x4 z = {0.f, 0.f, 0.f, 0.f};
    f32x4 c0 = z, c1 = z, c2 = z;
#pragma unroll
    for (int i = 0; i < 8; ++i) {
      frag_u ah, al;
      ah.q[0] = q[i][0];
      ah.q[1] = q[i][1];
      al.q[0] = q[i][2];
      al.q[1] = q[i][3];
      c0 = __builtin_amdgcn_mfma_f32_16x16x32_bf16(ah.v, Bh[i], c0, 0, 0, 0);
      c1 = __builtin_amdgcn_mfma_f32_16x16x32_bf16(ah.v, Bl[i], c1, 0, 0, 0);
      c2 = __builtin_amdgcn_mfma_f32_16x16x32_bf16(al.v, Bh[i], c2, 0, 0, 0);
    }
    const f32x4 rs = c0 + c1 + c2;

    *(f32x4*)&red[wv][lane][0] = rs;
    __syncthreads();
    // flag=s here proves: all waves' step-s loads retired (write-gate basis).
    // Posted drain-free, off the critical path.
    if (tid == 0)
      __hip_atomic_store(&flags[fown], s, __ATOMIC_RELAXED,
                         __HIP_MEMORY_SCOPE_AGENT);
    const float sum = red[0][lp][ri] + red[1][lp][ri] + red[2][lp][ri] +
                      red[3][lp][ri];
    float v = pre + (TR ? -sum : sum);  // TR=1 data was stored negated
    v = v > 0.f ? v : 0.f;

    // pack tagged (hv,lv): hi = TRUNC => lo >= 0 => both signs free for tag
    const unsigned short hv =
        (unsigned short)(__float_as_uint(v) >> 16);          // trunc, >= 0
    const float hf = __uint_as_float((unsigned)hv << 16);
    const unsigned short lv = (unsigned short)f2bf(v - hf);  // RNE, >= 0
    pk[r][cl] = (unsigned)(unsigned short)(hv ^ flip) |
                ((unsigned)(unsigned short)(lv ^ flip) << 16);
    __syncthreads();

    // wave 0: two fully-coalesced 64-lane 8 B tagged stores, NO drain --
    // landing is detected by consumers' sentinel polls.
    if (wv == 0) {
      unsigned long long hq = 0, lq2 = 0;
#pragma unroll
      for (int k = 0; k < 4; ++k) {
        const unsigned u = pk[pr][pc0 + k];
        hq |= ((unsigned long long)(u & 0xffffu)) << (16 * k);
        lq2 |= ((unsigned long long)(u >> 16)) << (16 * k);
      }
      char* dst = tbase + (size_t)(s & 3) * PAIRB;
      st_a8((unsigned long long*)(dst + 512 * w + 8 * lane), hq);
      st_a8((unsigned long long*)(dst + 32768 + 512 * w + 8 * lane), lq2);
    }
    // out writes off the critical chain
    out[oidx] = v;
    if (s == T_) outH[(size_t)b * H_ + c] = v;
  }
}

// ---------------------------------------------------------------------------
extern "C" void kernel_launch(void* const* d_in, const int* in_sizes, int n_in,
                              void* d_out, int out_size, void* d_ws,
                              size_t ws_size, hipStream_t stream) {
  const float* x = (const float*)d_in[0];   // [B,T,I]
  const float* Wi = (const float*)d_in[1];  // [H,I]
  const float* bi = (const float*)d_in[2];  // [H]
  const float* Wh = (const float*)d_in[3];  // [H,H]
  const float* bh = (const float*)d_in[4];  // [H]
  float* out = (float*)d_out;

  int* flags = (int*)d_ws;                       // 256 x 64 B = 16 KB
  char* planes = (char*)d_ws + 32768;            // 4 teams x 256 KB = 1 MB

  proj_gemm<<<2048, 256, 0, stream>>>(x, Wi, bi, bh, out);
  rnn_rec<<<NWG, 256, 0, stream>>>(Wh, out, planes, flags);
}